// Round 3
// baseline (266.222 us; speedup 1.0000x reference)
//
#include <hip/hip_runtime.h>
#include <cmath>

// Problem constants (fixed instantiation): x is [B, D] float32.
constexpr int B = 256;
constexpr int D = 512;
constexpr int ROW = D + D * D + D;          // 263168 floats per output row
constexpr int PAIR_ROWS_PER_BLOCK = 32;     // 32 rows x 128 float4-cols per block
constexpr int PAIR_BLOCKS = D / PAIR_ROWS_PER_BLOCK;  // 16
constexpr int BLOCKS_PER_BATCH = PAIR_BLOCKS + 1;     // +1 for sin+identity

// Native clang vector type — __builtin_nontemporal_store requires it
// (HIP's float4 is a struct and is rejected).
typedef float vfloat4 __attribute__((ext_vector_type(4)));

__device__ __forceinline__ void nt_store4(float* p, vfloat4 v) {
    __builtin_nontemporal_store(v, reinterpret_cast<vfloat4*>(p));  // global_store_dwordx4 ... nt
}

__global__ __launch_bounds__(256)
void basis_expansion_kernel(const float* __restrict__ x, float* __restrict__ out) {
    const int bid  = blockIdx.x;
    const int b    = bid / BLOCKS_PER_BATCH;
    const int part = bid % BLOCKS_PER_BATCH;
    const int t    = threadIdx.x;

    const float* xrow = x + b * D;
    float* orow = out + (size_t)b * ROW;

    __shared__ float sx[D];
    sx[t]       = xrow[t];
    sx[t + 256] = xrow[t + 256];
    __syncthreads();

    // Every thread owns one fixed float4 of the x row (column direction).
    const int col4 = t & 127;                 // 128 float4s cover D=512
    const vfloat4 v = reinterpret_cast<const vfloat4*>(sx)[col4];

    if (part == PAIR_BLOCKS) {
        // sin section (threads 0..127) + identity section (threads 128..255)
        if (t < 128) {
            vfloat4 s;
            s.x = sinf(v.x); s.y = sinf(v.y); s.z = sinf(v.z); s.w = sinf(v.w);
            nt_store4(orow + 4 * col4, s);
        } else {
            nt_store4(orow + D + D * D + 4 * col4, v);
        }
        return;
    }

    // Pair section: out[b, D + i*D + j] = x[b,i] * x[b,j]
    // Block covers rows [part*32, part*32+32). Per iteration m, threads
    // 0..127 (waves 0-1) handle row 2m, threads 128..255 (waves 2-3) row 2m+1,
    // so the 4 waves write one contiguous 4 KB span per iteration.
    const int row0 = part * PAIR_ROWS_PER_BLOCK + (t >> 7);
    float* pbase = orow + D;                  // 16B aligned (512 % 4 == 0)

#pragma unroll
    for (int m = 0; m < PAIR_ROWS_PER_BLOCK / 2; ++m) {
        const int row = row0 + 2 * m;
        const float a = sx[row];              // LDS broadcast (conflict-free)
        vfloat4 w = a * v;                    // vector fmul
        nt_store4(pbase + 4 * (row * 128 + col4), w);  // global_store_dwordx4 nt
    }
}

extern "C" void kernel_launch(void* const* d_in, const int* in_sizes, int n_in,
                              void* d_out, int out_size, void* d_ws, size_t ws_size,
                              hipStream_t stream) {
    const float* x = (const float*)d_in[0];
    float* out = (float*)d_out;
    dim3 grid(B * BLOCKS_PER_BATCH);
    dim3 block(256);
    basis_expansion_kernel<<<grid, block, 0, stream>>>(x, out);
}